// Round 3
// baseline (282.639 us; speedup 1.0000x reference)
//
#include <hip/hip_runtime.h>
#include <hip/hip_bf16.h>

// LinearAttention on MI355X. Pipeline (peak d_ws 66.3 MiB; K/V scratch in d_out):
//  norm_r -> xn_transpose(bf16,[b][pos][c]) -> weight casts ->
//  gemm_bt<1536,split3> (Q->ws, K/V->d_out) -> attn_kernel ->
//  gemm_bt<512,+bias> (bf16 pre) -> norm_r_bf16 -> final_scale_bf16 (fp32 out)
// MFMA = v_mfma_f32_16x16x32_bf16, layouts:
//  A: m=lane&15, k=(lane>>4)*8+j ; B: n=lane&15, k=(lane>>4)*8+j ;
//  C/D: col=lane&15, row=(lane>>4)*4+reg
// R8: 256x256 tile, BK=64, 4 phases/K-tile (as R7) but LDS planes [256][64]
//  (128B rows, full-line staging: R7's 64B-row K-half planes caused +52%
//  FETCH overfetch and naked vmcnt waits). Intra-line XOR swizzle
//  chunk' = chunk ^ (row&7): staging stays one full 128B line per 8-lane
//  group (source-permuted, dest lane-linear); frag reads bank-uniform.
//  Pieces = M-halves; all 8 loads of tile kt+1 issued at P0/P1 of kt;
//  single vmcnt(0) at P3 (2-phase gap covers load latency).

#define AS1 __attribute__((address_space(1)))
#define AS3 __attribute__((address_space(3)))

using short8 = __attribute__((ext_vector_type(8))) short;
using usht4  = __attribute__((ext_vector_type(4))) unsigned short;
using f32x4  = __attribute__((ext_vector_type(4))) float;

__device__ __forceinline__ unsigned short f2bf(float f) {
  unsigned int u = __float_as_uint(f);
  u += 0x7fffu + ((u >> 16) & 1u);          // RNE
  return (unsigned short)(u >> 16);
}
__device__ __forceinline__ float bf2f(unsigned short s) {
  return __uint_as_float(((unsigned int)s) << 16);
}

// ---------------------------------------------------------------------------
// K1: per-(b,pos) L2 norm factor r = sqrt(512)/max(||x||,1e-12), fp32 input
// X: [32][512][1024] fp32, R: [32][1024].  f32x4 loads, 16/thread.
__global__ __launch_bounds__(256, 4)
void norm_r(const float* __restrict__ X, float* __restrict__ R) {
  __shared__ float part[32][33];
  const int t = threadIdx.x;
  const int b = blockIdx.x >> 5;
  const int pos0 = (blockIdx.x & 31) * 32;
  const int pg = t & 7, cg = t >> 3;
  const float* xp = X + ((size_t)b * 512 + (size_t)cg * 16) * 1024 + pos0 + pg * 4;
  f32x4 s = {0.f, 0.f, 0.f, 0.f};
#pragma unroll
  for (int i = 0; i < 16; ++i) {
    f32x4 v = *(const f32x4*)(xp + (size_t)i * 1024);
    s += v * v;
  }
  part[cg][pg * 4 + 0] = s.x;
  part[cg][pg * 4 + 1] = s.y;
  part[cg][pg * 4 + 2] = s.z;
  part[cg][pg * 4 + 3] = s.w;
  __syncthreads();
  if (t < 32) {
    float tot = 0.f;
#pragma unroll
    for (int j = 0; j < 32; ++j) tot += part[j][t];
    R[(size_t)b * 1024 + pos0 + t] = 22.627416998f / fmaxf(sqrtf(tot), 1e-12f);
  }
}

// ---------------------------------------------------------------------------
// K7: same norm but bf16 input (pre): [32][512][1024] bf16
__global__ __launch_bounds__(256, 4)
void norm_r_bf16(const unsigned short* __restrict__ X, float* __restrict__ R) {
  __shared__ float part[16][64];
  const int t = threadIdx.x;
  const int b = blockIdx.x >> 4;
  const int pos0 = (blockIdx.x & 15) * 64;
  const int pg = t & 15, cg = t >> 4;
  const unsigned short* xp =
      X + ((size_t)b * 512 + (size_t)cg * 32) * 1024 + pos0 + pg * 4;
  float s0 = 0.f, s1 = 0.f, s2 = 0.f, s3 = 0.f;
#pragma unroll 8
  for (int i = 0; i < 32; ++i) {
    usht4 v = *(const usht4*)(xp + (size_t)i * 1024);
    float a = bf2f(v.x), bb = bf2f(v.y), c = bf2f(v.z), d = bf2f(v.w);
    s0 += a * a; s1 += bb * bb; s2 += c * c; s3 += d * d;
  }
  part[cg][pg * 4 + 0] = s0;
  part[cg][pg * 4 + 1] = s1;
  part[cg][pg * 4 + 2] = s2;
  part[cg][pg * 4 + 3] = s3;
  __syncthreads();
  if (t < 64) {
    float tot = 0.f;
#pragma unroll
    for (int j = 0; j < 16; ++j) tot += part[j][t];
    R[(size_t)b * 1024 + pos0 + t] = 22.627416998f / fmaxf(sqrtf(tot), 1e-12f);
  }
}

// ---------------------------------------------------------------------------
// K2: xn_T[b][pos][c] = bf16(x[b][c][pos] * r1[b][pos])   (g_in folded into W)
// Phase 2 emits 16B stores (short8).
__global__ __launch_bounds__(256, 4)
void xn_transpose(const float* __restrict__ X, const float* __restrict__ R,
                  unsigned short* __restrict__ XT) {
  __shared__ float tile[64][65];
  const int t = threadIdx.x;
  const int b = blockIdx.z, cb = blockIdx.y, pb = blockIdx.x;
  {
    const int p = t & 63, cg = t >> 6;
    const float r = R[(size_t)b * 1024 + pb * 64 + p];
    const float* xp = X + ((size_t)b * 512 + (size_t)(cb * 64 + cg * 16)) * 1024 + pb * 64 + p;
#pragma unroll
    for (int i = 0; i < 16; ++i)
      tile[cg * 16 + i][p] = xp[(size_t)i * 1024] * r;
  }
  __syncthreads();
#pragma unroll
  for (int k = 0; k < 2; ++k) {
    const int idx = k * 256 + t;
    const int p = idx >> 3, c8 = idx & 7;
    short8 v;
#pragma unroll
    for (int j = 0; j < 8; ++j) v[j] = (short)f2bf(tile[c8 * 8 + j][p]);
    *(short8*)(XT + ((size_t)b * 1024 + pb * 64 + p) * 512 + cb * 64 + c8 * 8) = v;
  }
}

// ---------------------------------------------------------------------------
// weight casts
__global__ __launch_bounds__(256, 4)
void cast_wqkv(const float* __restrict__ W, const float* __restrict__ g,
               unsigned short* __restrict__ O) {
  int i = blockIdx.x * 256 + threadIdx.x;      // 786432 total
  O[i] = f2bf(W[i] * g[i & 511]);
}
__global__ __launch_bounds__(256, 4)
void cast_w(const float* __restrict__ W, unsigned short* __restrict__ O, int n) {
  int i = blockIdx.x * 256 + threadIdx.x;
  if (i < n) O[i] = f2bf(W[i]);
}

// ---------------------------------------------------------------------------
// Shared GEMM: Out[b][m][n] = sum_k A[m][k]*Ball[b][n][k], bf16 out.
// A: [MTOT][512] bf16 ; Ball: [32][1024][512] bf16.
// LDS (elements, buffer p=kt&1): p*32768 + { A:0, B:16384 }, planes [256][64].
// Plane content: LDS(row, slot) = global(row, chunk slot ^ (row&7)); 16B chunks.
// Stage: 8-lane groups read one full (permuted) 128B line; dest lane-linear.
template <int MTOT, bool SPLIT3, bool BIAS>
__global__ __launch_bounds__(512, 2)
void gemm_bt(const unsigned short* __restrict__ A,
             const unsigned short* __restrict__ Ball,
             unsigned short* __restrict__ O0, unsigned short* __restrict__ O1,
             unsigned short* __restrict__ O2, const float* __restrict__ bias) {
  __shared__ __align__(16) unsigned short smem[65536];   // 128 KiB
  const int t = threadIdx.x;
  const int lane = t & 63, w = t >> 6;
  const int wm = w >> 2, wn = w & 3;
  const int mt = blockIdx.x >> 2, nt = blockIdx.x & 3;
  const int b = blockIdx.y;
  const unsigned short* Ag = A + (size_t)(mt * 256) * 512;
  const unsigned short* Bg = Ball + ((size_t)b * 1024 + (size_t)nt * 256) * 512;

  // staging: piece = M-half of one matrix ([128 rows][64] = 16 KiB, 2 loads/thr)
  // lane l of wave w, call j: row = half*128 + j*64 + w*8 + (l>>3), slot l&7
  // dest elem = plane + row*64 + (l&7)*8  (lane-linear: base + l*8)
  // source chunk = (l&7) ^ (row&7) = (l&7) ^ ((l>>3)&7)
  const int srow = w * 8 + (lane >> 3);
  const int schunk = ((lane & 7) ^ (lane >> 3)) * 8;
  const unsigned short* Asrc = Ag + (size_t)srow * 512 + schunk;
  const unsigned short* Bsrc = Bg + (size_t)srow * 512 + schunk;

  // fragment reads: row = base16 + fr, chunk = ks*4 + (lane>>4),
  // slot = chunk ^ (fr&7)   (row&7 == fr&7)
  const int fr = lane & 15;
  const int sw0 = ((lane >> 4) ^ (fr & 7)) << 3;      // ks=0 (elements)
  const int sw1 = sw0 ^ 32;                           // ks=1 (chunk^4 -> +-32)
  const int aRow = (wm * 128 + fr) * 64;
  const int bRow = (wn * 64 + fr) * 64;

  f32x4 acc[8][4] = {};

  auto STAGE = [&](int kt, int half, int isB) {
    const unsigned short* Xs = isB ? Bsrc : Asrc;
    unsigned short* dst = smem + (kt & 1) * 32768 + isB * 16384 +
                          half * 8192 + w * 512;
    const size_t ko = (size_t)kt * 64 + (size_t)(half * 128) * 512;
#pragma unroll
    for (int j = 0; j < 2; ++j)
      __builtin_amdgcn_global_load_lds(
          (const AS1 unsigned int*)(Xs + ko + (size_t)(j * 64) * 512),
          (AS3 unsigned int*)(dst + j * 4096), 16, 0, 0);
  };

#define GBAR() asm volatile("" ::: "memory"); \
               __builtin_amdgcn_s_barrier();  \
               asm volatile("" ::: "memory")
#define MFMA_BF16 __builtin_amdgcn_mfma_f32_16x16x32_bf16

  // prologue: stage all 4 pieces of tile 0, drain, barrier
  STAGE(0, 0, 0); STAGE(0, 0, 1); STAGE(0, 1, 0); STAGE(0, 1, 1);
  asm volatile("s_waitcnt vmcnt(0)" ::: "memory");
  GBAR();

#pragma unroll 1
  for (int kt = 0; kt < 8; ++kt) {
    const unsigned short* lAp = smem + (kt & 1) * 32768;
    const unsigned short* lBp = lAp + 16384;
    short8 af[8], bf0, bf1;

    // -------- P0: ks=0, j=0,1 ; stage A-h0,B-h0 of kt+1 --------
#pragma unroll
    for (int i = 0; i < 8; ++i)
      af[i] = *(const short8*)(lAp + aRow + i * 1024 + sw0);
    bf0 = *(const short8*)(lBp + bRow + sw0);
    bf1 = *(const short8*)(lBp + bRow + 1024 + sw0);
    if (kt < 7) { STAGE(kt + 1, 0, 0); STAGE(kt + 1, 0, 1); }
    GBAR();
    __builtin_amdgcn_sched_barrier(0);
    __builtin_amdgcn_s_setprio(1);
#pragma unroll
    for (int i = 0; i < 8; ++i) {
      acc[i][0] = MFMA_BF16(af[i], bf0, acc[i][0], 0, 0, 0);
      acc[i][1] = MFMA_BF16(af[i], bf1, acc[i][1], 0, 0, 0);
    }
    __builtin_amdgcn_s_setprio(0);
    GBAR();

    // -------- P1: ks=0, j=2,3 ; stage A-h1,B-h1 of kt+1 --------
    bf0 = *(const short8*)(lBp + bRow + 2048 + sw0);
    bf1 = *(const short8*)(lBp + bRow + 3072 + sw0);
    if (kt < 7) { STAGE(kt + 1, 1, 0); STAGE(kt + 1, 1, 1); }
    GBAR();
    __builtin_amdgcn_sched_barrier(0);
    __builtin_amdgcn_s_setprio(1);
#pragma unroll
    for (int i = 0; i < 8; ++i) {
      acc[i][2] = MFMA_BF16(af[i], bf0, acc[i][2], 0, 0, 0);
      acc[i][3] = MFMA_BF16(af[i], bf1, acc[i][3], 0, 0, 0);
    }
    __builtin_amdgcn_s_setprio(0);
    GBAR();

    // -------- P2: ks=1, j=0,1 --------
#pragma unroll
    for (int i = 0; i < 8; ++i)
      af[i] = *(const short8*)(lAp + aRow + i * 1024 + sw1);
    bf0 = *(const short8*)(lBp + bRow + sw1);
    bf1 = *(const short8*)(lBp + bRow + 1024 + sw1);
    GBAR();
    __builtin_amdgcn_sched_barrier(0);
    __builtin_amdgcn_s_setprio(1);
#pragma unroll
    for (int i = 0; i < 8; ++i) {
      acc[i][0] = MFMA_BF16(af[i], bf0, acc[i][0], 0, 0, 0);
      acc[i][1] = MFMA_BF16(af[i], bf1, acc[i][1], 0, 0, 0);
    }
    __builtin_amdgcn_s_setprio(0);
    GBAR();

    // -------- P3: ks=1, j=2,3 ; confirm tile kt+1 fully staged --------
    bf0 = *(const short8*)(lBp + bRow + 2048 + sw1);
    bf1 = *(const short8*)(lBp + bRow + 3072 + sw1);
    asm volatile("s_waitcnt vmcnt(0)" ::: "memory");
    GBAR();
    __builtin_amdgcn_sched_barrier(0);
    __builtin_amdgcn_s_setprio(1);
#pragma unroll
    for (int i = 0; i < 8; ++i) {
      acc[i][2] = MFMA_BF16(af[i], bf0, acc[i][2], 0, 0, 0);
      acc[i][3] = MFMA_BF16(af[i], bf1, acc[i][3], 0, 0, 0);
    }
    __builtin_amdgcn_s_setprio(0);
    GBAR();
  }

  // epilogue: per-wave [128][64] bf16 C stage with cross-octant XOR
  // col ^= ((j^g)<<4) pattern (conflict-free write+read, verified R7).
  __syncthreads();
  unsigned short* Cw = smem + w * 8192;
  const int g = lane >> 4, l15 = lane & 15;
#pragma unroll
  for (int i = 0; i < 8; ++i)
#pragma unroll
    for (int j = 0; j < 4; ++j) {
      const int cs = ((j ^ g) << 4) + l15;
#pragma unroll
      for (int r = 0; r < 4; ++r) {
        const int row = i * 16 + g * 4 + r;
        float v = acc[i][j][r];
        if (BIAS) v += bias[mt * 256 + wm * 128 + row];
        Cw[row * 64 + cs] = f2bf(v);
      }
    }
  unsigned short* OgW;
  if (SPLIT3) {
    const int sec = mt >> 1;                   // 512-row sections: Q,K,V
    unsigned short* base = (sec == 0) ? O0 : ((sec == 1) ? O1 : O2);
    OgW = base + ((size_t)b * 512 + (size_t)((mt & 1) * 256 + wm * 128)) * 1024 +
          nt * 256 + wn * 64;
  } else {
    OgW = O0 + ((size_t)b * MTOT + (size_t)(mt * 256 + wm * 128)) * 1024 +
          nt * 256 + wn * 64;
  }
#pragma unroll
  for (int p = 0; p < 16; ++p) {
    const int row = p * 8 + (lane >> 3);
    const int q2 = (row >> 2) & 3;
    const int slot = (lane & 7) ^ (q2 << 1);
    short8 v = *(const short8*)(Cw + row * 64 + slot * 8);
    *(short8*)(OgW + (size_t)row * 1024 + (lane & 7) * 8) = v;
  }
#undef GBAR
#undef MFMA_BF16
}

// ---------------------------------------------------------------------------
// K5: attention per (b,h). Q/K/V: [32][512][1024] bf16 each.
// outT: [32][1024][512] bf16.  K/V staged with 16B loads (R5).
__global__ __launch_bounds__(256, 2)
void attn_kernel(const unsigned short* __restrict__ Qp,
                 const unsigned short* __restrict__ Kp,
                 const unsigned short* __restrict__ Vp,
                 const float* __restrict__ memkv,
                 unsigned short* __restrict__ outT) {
  __shared__ char smem[36608];
  unsigned short* bufA = (unsigned short*)smem;            // [64][72] expK / expQ^T
  unsigned short* bufB = (unsigned short*)(smem + 9216);   // [64][72] V / C^T
  float* Pl   = (float*)(smem + 18432);                    // [512] rowsum partials
  float* Pc   = (float*)(smem + 18432);                    // [4][64] colsum (Q phase)
  float* csS  = (float*)(smem + 21504);                    // [64]
  float* msum = (float*)(smem + 35072);                    // [64][4]
  float* rsI  = (float*)(smem + 36096);                    // [64]
  const int t = threadIdx.x;
  const int lane = t & 63, wave = t >> 6;
  const int b = blockIdx.x >> 3, h = blockIdx.x & 7;
  const size_t hb = ((size_t)b * 512 + (size_t)h * 64) * 1024;
  const unsigned short* Qg = Qp + hb;
  const unsigned short* Kg = Kp + hb;
  const unsigned short* Vg = Vp + hb;
  const float* mk = memkv + (size_t)h * 256;
  const float* mv = memkv + 2048 + (size_t)h * 256;

  float rsum[2] = {0.f, 0.f};
  f32x4 cacc[4] = {};

  // ---- context: C_raw[d][e] = sum_n exp(K[d][n]) * V[e][n], n over mem+1024
  for (int it = 0; it < 17; ++it) {
    if (it == 0) {                                   // mem tile (cols 0..3, rest 0)
      const int d = t & 63, j = t >> 6;
      const float ev = __expf(mk[d * 4 + j]);
      msum[d * 4 + j] = ev;
      bufA[d * 72 + j] = f2bf(ev);
      bufB[d * 72 + j] = f2bf(mv[d * 4 + j]);
      for (int c2 = 4 + j; c2 < 64; c2 += 4) {
        bufA[d * 72 + c2] = 0;
        bufB[d * 72 + c2] = 0;
      }
    } else {
      const int c0 = (it - 1) * 64;
#pragma unroll
      for (int z = 0; z < 2; ++z) {
        const int d = z * 32 + (t >> 3), ch = t & 7;
        short8 kv = *(const short8*)(Kg + (size_t)d * 1024 + c0 + ch * 8);
        short8 pk;
        float ssum = 0.f;
#pragma unroll
        for (int j = 0; j < 8; ++j) {
          const float e = __expf(bf2f((unsigned short)kv[j]));
          ssum += e;
          pk[j] = (short)f2bf(e);
        }
        rsum[z] += ssum;
        *(short8*)(bufA + d * 72 + ch * 8) = pk;
        short8 vv = *(const short8*)(Vg + (size_t)d * 1024 + c0 + ch * 8);
        *(short8*)(bufB + d * 72 + ch * 8) = vv;
      }
    }
    __syncthreads();
#pragma unroll
    for (int ks = 0; ks < 2; ++ks) {
      short8 a = *(const short8*)(bufA + (wave * 16 + (lane & 15)) * 72 +
                                  ks * 32 + (lane >> 4) * 8);
#pragma unroll
      for (int et = 0; et < 4; ++et) {
        short8 bb = *(const short8*)(bufB + (et * 16 + (lane & 15)) * 72 +
                                     ks * 32 + (lane >> 4) * 8);
        cacc[et] = __builtin_amdgcn_mfma_f32_16x16x32_bf16(a, bb, cacc[et], 0, 0, 0);
      }
    }
    __syncthreads();
  }

  // ---- rowsum reduce (k softmax denominators): Pl[(d,ch)] = partial
  Pl[t]       = rsum[0];     // d = t>>3, ch = t&7  -> index d*8+ch = t
  Pl[256 + t] = rsum[1];
  __syncthreads();
  if (t < 64) {
    float s = 0.f;
#pragma unroll
    for (int ch = 0; ch < 8; ++ch) s += Pl[t * 8 + ch];
    s += msum[t * 4] + msum[t * 4 + 1] + msum[t * 4 + 2] + msum[t * 4 + 3];
    rsI[t] = 1.0f / s;
  }
  __syncthreads();

  // ---- C^T into LDS (bf16), folding 1/rowsum[d]
  unsigned short* CT = bufB;                         // staged V is dead
#pragma unroll
  for (int et = 0; et < 4; ++et)
#pragma unroll
    for (int r = 0; r < 4; ++r) {
      const int d = wave * 16 + (lane >> 4) * 4 + r;
      const int e = et * 16 + (lane & 15);
      CT[e * 72 + d] = f2bf(cacc[et][r] * rsI[d]);
    }
  __syncthreads();

  short8 a0 = *(const short8*)(CT + (wave * 16 + (lane & 15)) * 72 + (lane >> 4) * 8);
  short8 a1 = *(const short8*)(CT + (wave * 16 + (lane & 15)) * 72 + 32 + (lane >> 4) * 8);
  unsigned short* oBase = outT + (size_t)b * 1024 * 512 + h * 64;

  // ---- out[e][p] = sum_d C^T[e][d]*expQ[d][p] * scale/colsum[p]
  for (int pt = 0; pt < 16; ++pt) {
    {
      const int p = lane, dq = wave;
      float cp = 0.f;
#pragma unroll
      for (int i2 = 0; i2 < 8; ++i2) {
        const int d0 = dq * 16 + i2 * 2;
        const float e0 = __expf(bf2f(Qg[(size_t)d0 * 1024 + pt * 64 + p]));
        const float e1 = __expf(bf2f(Qg[(size_t)(d0 + 1) * 1024 + pt * 64 + p]));
        cp += e0 + e1;
        const unsigned int pk =
            (unsigned int)f2bf(e0) | ((unsigned int)f2bf(e1) << 16);
        *(unsigned int*)(bufA + p * 72 + d0) = pk;   // expQ^T[p][d]
      }
      Pc[dq * 64 + p] = cp;
    }
    __syncthreads();
    if (t < 64) csS[t] = 0.125f / (Pc[t] + Pc[64 + t] + Pc[128 + t] + Pc[192 + t]);
    __syncthreads();
#pragma unroll
    for (int ps = 0; ps < 4; ++ps) {
      f32x4 oc = {};
      short8 b0 = *(const short8*)(bufA + (ps * 16 + (lane & 15)) * 72 + (lane >> 4) * 8);
      short8 b1 = *(const short8*)(bufA + (ps * 16 + (lane & 15)) * 72 + 32 + (lane >> 4) * 8);
      oc = __builtin_amdgcn_mfma_f32_16x16x32_bf16(a0, b0, oc, 0, 0, 0);
      oc = __builtin_amdgcn_mfma_f32_16x16x32_bf16(a1, b1, oc, 0, 0, 0);
      const float cs = csS[ps * 16 + (lane & 15)];
      const unsigned long long pk =
          (unsigned long long)f2bf(oc[0] * cs) |
          ((unsigned long long)f2bf(oc[1] * cs) << 16) |
          ((unsigned long long)f2bf(oc[2] * cs) << 32) |
          ((unsigned long long)f2bf(oc[3] * cs) << 48);
      const int p = pt * 64 + ps * 16 + (lane & 15);
      *(unsigned long long*)(oBase + (size_t)p * 512 + wave * 16 + (lane >> 4) * 4) = pk;
    }
    __syncthreads();
  }
}

// ---------------------------------------------------------------------------
// K8: out[b][c][p] = bf2f(pre[b][c][p]) * r2[b][p] * g_out[c]   (fp32 out)
__global__ __launch_bounds__(256, 4)
void final_scale_bf16(const unsigned short* __restrict__ P,
                      const float* __restrict__ R, const float* __restrict__ G,
                      float* __restrict__ O) {
  const size_t f = ((size_t)blockIdx.x * 256 + threadIdx.x) * 4;
  const int p = (int)(f & 1023);
  const int c = (int)((f >> 10) & 511);
  const int b = (int)(f >> 19);
  usht4 v = *(const usht4*)(P + f);
  const f32x4 r = *(const f32x4*)(R + (size_t)b * 1024 + p);
  const float g = G[c];
  f32x4 o;
  o.x = bf2f(v.x) * r.x * g;
  o.y = bf2f(v.y) * r.y * g;
  o.z = bf2f(v.z) * r.z * g;
  o.w = bf2f(v.w) * r.w * g;
  *(f32x4*)(O + f) = o;
}

// ---------------------------------------------------------------------------
extern "C" void kernel_launch(void* const* d_in, const int* in_sizes, int n_in,
                              void* d_out, int out_size, void* d_ws, size_t ws_size,
                              hipStream_t stream) {
  (void)in_sizes; (void)n_in; (void)out_size; (void)ws_size;
  const float* x     = (const float*)d_in[0];
  const float* g_in  = (const float*)d_in[1];
  const float* w_qkv = (const float*)d_in[2];
  const float* memkv = (const float*)d_in[3];
  const float* w_out = (const float*)d_in[4];
  const float* b_out = (const float*)d_in[5];
  const float* g_out = (const float*)d_in[6];
  float* out = (float*)d_out;

  // d_ws layout — peak 69,468,160 B (66.3 MiB)
  char* ws = (char*)d_ws;
  float* r1           = (float*)ws;                        // 128 KiB
  float* r2           = (float*)(ws + 131072);             // 128 KiB
  unsigned short* wqb = (unsigned short*)(ws + 262144);    // 1.5 MiB
  unsigned short* wob = (unsigned short*)(ws + 1835008);   // 0.5 MiB
  unsigned short* xnT = (unsigned short*)(ws + 2359296);   // 32 MiB (→ outT)
  unsigned short* Qp  = (unsigned short*)(ws + 35913728);  // 32 MiB (→ pre)
  unsigned short* outT = xnT;
  unsigned short* pre  = Qp;
  // K/V live in d_out (exactly 64 MiB); d_out fully rewritten by final_scale.
  unsigned short* Kp  = (unsigned short*)d_out;
  unsigned short* Vp  = (unsigned short*)d_out + 16777216;

  norm_r<<<1024, 256, 0, stream>>>(x, r1);
  xn_transpose<<<dim3(16, 8, 32), 256, 0, stream>>>(x, r1, xnT);
  cast_wqkv<<<3072, 256, 0, stream>>>(w_qkv, g_in, wqb);
  cast_w<<<1024, 256, 0, stream>>>(w_out, wob, 262144);
  gemm_bt<1536, true, false><<<dim3(24, 32), 512, 0, stream>>>(
      wqb, xnT, Qp, Kp, Vp, nullptr);
  attn_kernel<<<256, 256, 0, stream>>>(Qp, Kp, Vp, memkv, outT);
  gemm_bt<512, false, true><<<dim3(8, 32), 512, 0, stream>>>(
      wob, outT, pre, nullptr, nullptr, b_out);
  norm_r_bf16<<<512, 256, 0, stream>>>(pre, r2);
  final_scale_bf16<<<16384, 256, 0, stream>>>(pre, r2, g_out, out);
}

// Round 4
// 256.426 us; speedup vs baseline: 1.1022x; 1.1022x over previous
//
#include <hip/hip_runtime.h>
#include <hip/hip_bf16.h>

// LinearAttention on MI355X. Pipeline (peak d_ws 66.3 MiB; K/V scratch in d_out):
//  xnorm_t (fused norm+transpose, x read ONCE) -> weight casts ->
//  gemm_bt<1536,split3> (Q->ws, K/V->d_out) -> attn_kernel ->
//  gemm_bt<512,+bias> (bf16 pre) -> norm_scale (fused norm+scale, pre read ONCE)
// MFMA = v_mfma_f32_16x16x32_bf16, layouts:
//  A: m=lane&15, k=(lane>>4)*8+j ; B: n=lane&15, k=(lane>>4)*8+j ;
//  C/D: col=lane&15, row=(lane>>4)*4+reg
// R9: gemm_bt reverted to R5 (128x128 tile, 34.8KiB LDS, proven 60us; the
//  256x256 deep-pipeline ports R6-R8 were all 65-68us on this K=512 shape).
//  norm_r+xn_transpose fused into xnorm_t ([512][32] strip in LDS, saves a
//  full 128MiB x re-read). norm_r_bf16+final_scale fused into norm_scale
//  ([512][64] strip in LDS, saves a 32MiB pre re-read). 7 launches (was 9).

#define AS1 __attribute__((address_space(1)))
#define AS3 __attribute__((address_space(3)))

using short8 = __attribute__((ext_vector_type(8))) short;
using usht4  = __attribute__((ext_vector_type(4))) unsigned short;
using f32x2  = __attribute__((ext_vector_type(2))) float;
using f32x4  = __attribute__((ext_vector_type(4))) float;

__device__ __forceinline__ unsigned short f2bf(float f) {
  unsigned int u = __float_as_uint(f);
  u += 0x7fffu + ((u >> 16) & 1u);          // RNE
  return (unsigned short)(u >> 16);
}
__device__ __forceinline__ float bf2f(unsigned short s) {
  return __uint_as_float(((unsigned int)s) << 16);
}

// ---------------------------------------------------------------------------
// K1 (fused): per (b, 32-pos strip): load x[b][0:512][strip] into LDS while
// accumulating per-pos sumsq; r = sqrt(512)/max(||x||,1e-12); then write
// xn_T[b][pos][c] = bf16(x*r) transposed. x read ONCE total.
// LDS: tile[512][34] f32 (69,632B, f32x2-aligned stores, 2-way-free scalar
// reads in transpose: bank=(2c+p)%32, 16*c8%32 in {0,16}); part[32][33]; r[32].
__global__ __launch_bounds__(256, 2)
void xnorm_t(const float* __restrict__ X, unsigned short* __restrict__ XT) {
  __shared__ float tile[512][34];
  __shared__ float part[32][33];
  __shared__ float rloc[32];
  const int t = threadIdx.x;
  const int b = blockIdx.x >> 5;
  const int pos0 = (blockIdx.x & 31) * 32;
  const int pr = t & 7, cr = t >> 3;            // pr: 4-pos chunk, cr: row in 32-group
  const float* xp = X + ((size_t)b * 512 + cr) * 1024 + pos0 + pr * 4;
  f32x4 ssq = {0.f, 0.f, 0.f, 0.f};
#pragma unroll
  for (int i = 0; i < 16; ++i) {
    f32x4 v = *(const f32x4*)(xp + (size_t)(i * 32) * 1024);
    ssq += v * v;
    f32x2 lo = {v.x, v.y}, hi = {v.z, v.w};
    *(f32x2*)(&tile[i * 32 + cr][pr * 4]) = lo;       // 136c+16pr: 8B-aligned
    *(f32x2*)(&tile[i * 32 + cr][pr * 4 + 2]) = hi;
  }
  part[cr][pr * 4 + 0] = ssq.x;
  part[cr][pr * 4 + 1] = ssq.y;
  part[cr][pr * 4 + 2] = ssq.z;
  part[cr][pr * 4 + 3] = ssq.w;
  __syncthreads();
  if (t < 32) {
    float tot = 0.f;
#pragma unroll
    for (int j = 0; j < 32; ++j) tot += part[j][t];
    rloc[t] = 22.627416998f / fmaxf(sqrtf(tot), 1e-12f);
  }
  __syncthreads();
#pragma unroll
  for (int k = 0; k < 8; ++k) {
    const int idx = k * 256 + t;
    const int p = idx >> 6, c8 = idx & 63;      // one pos per wave, 64 c-chunks
    const float r = rloc[p];
    short8 v;
#pragma unroll
    for (int j = 0; j < 8; ++j) v[j] = (short)f2bf(tile[c8 * 8 + j][p] * r);
    *(short8*)(XT + ((size_t)b * 1024 + pos0 + p) * 512 + c8 * 8) = v;
  }
}

// ---------------------------------------------------------------------------
// K6 (fused): per (b, 64-pos strip): load pre[b][0:512][strip] (bf16) into LDS
// with per-pos sumsq; r2 = sqrt(512)/max(||pre||,1e-12); write
// out[b][c][p] = bf2f(pre)*r2[p]*g_out[c] (fp32). pre read ONCE total.
// LDS: tile[512][68] ushort (69,632B, usht4-aligned: 136c+8*x);
// part[32][64] f32 (rloc reused from part after reduce).
__global__ __launch_bounds__(256, 2)
void norm_scale(const unsigned short* __restrict__ P, const float* __restrict__ G,
                float* __restrict__ O) {
  __shared__ unsigned short tile[512][68];
  __shared__ float part[2048];                  // [32][64]; then rloc = part[0:64]
  const int t = threadIdx.x;
  const int b = blockIdx.x >> 4;
  const int pos0 = (blockIdx.x & 15) * 64;
  const int pg = t & 7, cr = t >> 3;            // pg: 8-pos chunk, cr: row in 32-group
  const unsigned short* pp = P + ((size_t)b * 512 + cr) * 1024 + pos0 + pg * 8;
  float s[8] = {};
#pragma unroll
  for (int i = 0; i < 16; ++i) {
    short8 v = *(const short8*)(pp + (size_t)(i * 32) * 1024);
    usht4 lo = {(unsigned short)v[0], (unsigned short)v[1],
                (unsigned short)v[2], (unsigned short)v[3]};
    usht4 hi = {(unsigned short)v[4], (unsigned short)v[5],
                (unsigned short)v[6], (unsigned short)v[7]};
    *(usht4*)(&tile[i * 32 + cr][pg * 8]) = lo;
    *(usht4*)(&tile[i * 32 + cr][pg * 8 + 4]) = hi;
#pragma unroll
    for (int j = 0; j < 8; ++j) {
      const float f = bf2f((unsigned short)v[j]);
      s[j] += f * f;
    }
  }
#pragma unroll
  for (int j = 0; j < 8; ++j) part[cr * 64 + pg * 8 + j] = s[j];
  __syncthreads();
  if (t < 64) {
    float tot = 0.f;
#pragma unroll
    for (int j = 0; j < 32; ++j) tot += part[j * 64 + t];
    part[t] = 22.627416998f / fmaxf(sqrtf(tot), 1e-12f);   // rloc[t]
  }
  __syncthreads();
#pragma unroll
  for (int k = 0; k < 32; ++k) {
    const int idx = k * 256 + t;
    const int c = idx >> 4, p4 = idx & 15;
    usht4 v = *(const usht4*)(&tile[c][p4 * 4]);
    const float g = G[c];
    f32x4 o;
    o.x = bf2f(v.x) * part[p4 * 4 + 0] * g;
    o.y = bf2f(v.y) * part[p4 * 4 + 1] * g;
    o.z = bf2f(v.z) * part[p4 * 4 + 2] * g;
    o.w = bf2f(v.w) * part[p4 * 4 + 3] * g;
    *(f32x4*)(O + ((size_t)b * 512 + c) * 1024 + pos0 + p4 * 4) = o;
  }
}

// ---------------------------------------------------------------------------
// weight casts
__global__ __launch_bounds__(256, 4)
void cast_wqkv(const float* __restrict__ W, const float* __restrict__ g,
               unsigned short* __restrict__ O) {
  int i = blockIdx.x * 256 + threadIdx.x;      // 786432 total
  O[i] = f2bf(W[i] * g[i & 511]);
}
__global__ __launch_bounds__(256, 4)
void cast_w(const float* __restrict__ W, unsigned short* __restrict__ O, int n) {
  int i = blockIdx.x * 256 + threadIdx.x;
  if (i < n) O[i] = f2bf(W[i]);
}

// ---------------------------------------------------------------------------
// Shared GEMM (R5 structure, proven 60us): Out[b][m][n] = sum_k A[m][k]*Ball[b][n][k].
// A: [MTOT][512] bf16 ; Ball: [32][1024][512] bf16. 128x128 tile, BK=64.
// LDS XOR swizzle: LDS[row][pc] holds global chunk (pc ^ (row&7)); staging
// source col permuted per lane so global_load_lds dest stays lane-linear.
template <int MTOT, bool SPLIT3, bool BIAS>
__global__ __launch_bounds__(256, 2)
void gemm_bt(const unsigned short* __restrict__ A,
             const unsigned short* __restrict__ Ball,
             unsigned short* __restrict__ O0, unsigned short* __restrict__ O1,
             unsigned short* __restrict__ O2, const float* __restrict__ bias) {
  __shared__ char smem[34816];
  unsigned short* lA = (unsigned short*)smem;        // [128][64] swizzled
  unsigned short* lB = lA + 128 * 64;                // [128][64] swizzled
  const int t = threadIdx.x;
  const int lane = t & 63, w = t >> 6;
  const int wm = w >> 1, wn = w & 1;
  const int mt = blockIdx.x >> 3, nt = blockIdx.x & 7;
  const int b = blockIdx.y;
  const unsigned short* Ag = A + (size_t)(mt * 128) * 512;
  const unsigned short* Bg = Ball + ((size_t)b * 1024 + (size_t)nt * 128) * 512;
  const int scol = ((lane & 7) ^ (lane >> 3)) * 8;   // swizzled source chunk
  f32x4 acc[4][4] = {};

  for (int kt = 0; kt < 8; ++kt) {
    const unsigned short* As = Ag + kt * 64 + scol;
    const unsigned short* Bs = Bg + kt * 64 + scol;
#pragma unroll
    for (int i = 0; i < 4; ++i) {
      const int r = w * 32 + i * 8 + (lane >> 3);
      __builtin_amdgcn_global_load_lds(
          (const AS1 unsigned int*)(As + (size_t)r * 512),
          (AS3 unsigned int*)(lA + (w * 32 + i * 8) * 64), 16, 0, 0);
      __builtin_amdgcn_global_load_lds(
          (const AS1 unsigned int*)(Bs + (size_t)r * 512),
          (AS3 unsigned int*)(lB + (w * 32 + i * 8) * 64), 16, 0, 0);
    }
    __syncthreads();
#pragma unroll
    for (int ks = 0; ks < 2; ++ks) {
      const int pch = ((ks * 4 + (lane >> 4)) ^ (lane & 7)) * 8;  // row&7==lane&7
      short8 af[4], bfv[4];
#pragma unroll
      for (int i = 0; i < 4; ++i)
        af[i] = *(const short8*)(lA + (wm * 64 + i * 16 + (lane & 15)) * 64 + pch);
#pragma unroll
      for (int j = 0; j < 4; ++j)
        bfv[j] = *(const short8*)(lB + (wn * 64 + j * 16 + (lane & 15)) * 64 + pch);
#pragma unroll
      for (int i = 0; i < 4; ++i)
#pragma unroll
        for (int j = 0; j < 4; ++j)
          acc[i][j] = __builtin_amdgcn_mfma_f32_16x16x32_bf16(af[i], bfv[j],
                                                              acc[i][j], 0, 0, 0);
    }
    __syncthreads();
  }

  // epilogue: stage bf16 tile in LDS, stream out coalesced 16B stores
  unsigned short* Cst = (unsigned short*)smem;       // [128][136]
#pragma unroll
  for (int i = 0; i < 4; ++i)
#pragma unroll
    for (int j = 0; j < 4; ++j)
#pragma unroll
      for (int r = 0; r < 4; ++r) {
        const int row = wm * 64 + i * 16 + (lane >> 4) * 4 + r;
        const int col = wn * 64 + j * 16 + (lane & 15);
        float v = acc[i][j][r];
        if (BIAS) v += bias[mt * 128 + row];
        Cst[row * 136 + col] = f2bf(v);
      }
  __syncthreads();
  unsigned short* Og;
  if (SPLIT3) {
    const int sec = mt >> 2;
    unsigned short* base = (sec == 0) ? O0 : ((sec == 1) ? O1 : O2);
    Og = base + ((size_t)b * 512 + (size_t)(mt & 3) * 128) * 1024 + (size_t)nt * 128;
  } else {
    Og = O0 + ((size_t)b * MTOT + (size_t)mt * 128) * 1024 + (size_t)nt * 128;
  }
#pragma unroll
  for (int k = 0; k < 8; ++k) {
    const int f = t + k * 256;
    const int row = f >> 4, c8 = f & 15;
    short8 v = *(const short8*)(Cst + row * 136 + c8 * 8);
    *(short8*)(Og + (size_t)row * 1024 + c8 * 8) = v;
  }
}

// ---------------------------------------------------------------------------
// K5: attention per (b,h). Q/K/V: [32][512][1024] bf16 each.
// outT: [32][1024][512] bf16.  K/V staged with 16B loads (R5).
__global__ __launch_bounds__(256, 2)
void attn_kernel(const unsigned short* __restrict__ Qp,
                 const unsigned short* __restrict__ Kp,
                 const unsigned short* __restrict__ Vp,
                 const float* __restrict__ memkv,
                 unsigned short* __restrict__ outT) {
  __shared__ char smem[36608];
  unsigned short* bufA = (unsigned short*)smem;            // [64][72] expK / expQ^T
  unsigned short* bufB = (unsigned short*)(smem + 9216);   // [64][72] V / C^T
  float* Pl   = (float*)(smem + 18432);                    // [512] rowsum partials
  float* Pc   = (float*)(smem + 18432);                    // [4][64] colsum (Q phase)
  float* csS  = (float*)(smem + 21504);                    // [64]
  float* msum = (float*)(smem + 35072);                    // [64][4]
  float* rsI  = (float*)(smem + 36096);                    // [64]
  const int t = threadIdx.x;
  const int lane = t & 63, wave = t >> 6;
  const int b = blockIdx.x >> 3, h = blockIdx.x & 7;
  const size_t hb = ((size_t)b * 512 + (size_t)h * 64) * 1024;
  const unsigned short* Qg = Qp + hb;
  const unsigned short* Kg = Kp + hb;
  const unsigned short* Vg = Vp + hb;
  const float* mk = memkv + (size_t)h * 256;
  const float* mv = memkv + 2048 + (size_t)h * 256;

  float rsum[2] = {0.f, 0.f};
  f32x4 cacc[4] = {};

  // ---- context: C_raw[d][e] = sum_n exp(K[d][n]) * V[e][n], n over mem+1024
  for (int it = 0; it < 17; ++it) {
    if (it == 0) {                                   // mem tile (cols 0..3, rest 0)
      const int d = t & 63, j = t >> 6;
      const float ev = __expf(mk[d * 4 + j]);
      msum[d * 4 + j] = ev;
      bufA[d * 72 + j] = f2bf(ev);
      bufB[d * 72 + j] = f2bf(mv[d * 4 + j]);
      for (int c2 = 4 + j; c2 < 64; c2 += 4) {
        bufA[d * 72 + c2] = 0;
        bufB[d * 72 + c2] = 0;
      }
    } else {
      const int c0 = (it - 1) * 64;
#pragma unroll
      for (int z = 0; z < 2; ++z) {
        const int d = z * 32 + (t >> 3), ch = t & 7;
        short8 kv = *(const short8*)(Kg + (size_t)d * 1024 + c0 + ch * 8);
        short8 pk;
        float ssum = 0.f;
#pragma unroll
        for (int j = 0; j < 8; ++j) {
          const float e = __expf(bf2f((unsigned short)kv[j]));
          ssum += e;
          pk[j] = (short)f2bf(e);
        }
        rsum[z] += ssum;
        *(short8*)(bufA + d * 72 + ch * 8) = pk;
        short8 vv = *(const short8*)(Vg + (size_t)d * 1024 + c0 + ch * 8);
        *(short8*)(bufB + d * 72 + ch * 8) = vv;
      }
    }
    __syncthreads();
#pragma unroll
    for (int ks = 0; ks < 2; ++ks) {
      short8 a = *(const short8*)(bufA + (wave * 16 + (lane & 15)) * 72 +
                                  ks * 32 + (lane >> 4) * 8);
#pragma unroll
      for (int et = 0; et < 4; ++et) {
        short8 bb = *(const short8*)(bufB + (et * 16 + (lane & 15)) * 72 +
                                     ks * 32 + (lane >> 4) * 8);
        cacc[et] = __builtin_amdgcn_mfma_f32_16x16x32_bf16(a, bb, cacc[et], 0, 0, 0);
      }
    }
    __syncthreads();
  }

  // ---- rowsum reduce (k softmax denominators): Pl[(d,ch)] = partial
  Pl[t]       = rsum[0];     // d = t>>3, ch = t&7  -> index d*8+ch = t
  Pl[256 + t] = rsum[1];
  __syncthreads();
  if (t < 64) {
    float s = 0.f;
#pragma unroll
    for (int ch = 0; ch < 8; ++ch) s += Pl[t * 8 + ch];
    s += msum[t * 4] + msum[t * 4 + 1] + msum[t * 4 + 2] + msum[t * 4 + 3];
    rsI[t] = 1.0f / s;
  }
  __syncthreads();

  // ---- C^T into LDS (bf16), folding 1/rowsum[d]
  unsigned short* CT = bufB;                         // staged V is dead
#pragma unroll
  for (int et = 0; et < 4; ++et)
#pragma unroll
    for (int r = 0; r < 4; ++r) {
      const int d = wave * 16 + (lane >> 4) * 4 + r;
      const int e = et * 16 + (lane & 15);
      CT[e * 72 + d] = f2bf(cacc[et][r] * rsI[d]);
    }
  __syncthreads();

  short8 a0 = *(const short8*)(CT + (wave * 16 + (lane & 15)) * 72 + (lane >> 4) * 8);
  short8 a1 = *(const short8*)(CT + (wave * 16 + (lane & 15)) * 72 + 32 + (lane >> 4) * 8);
  unsigned short* oBase = outT + (size_t)b * 1024 * 512 + h * 64;

  // ---- out[e][p] = sum_d C^T[e][d]*expQ[d][p] * scale/colsum[p]
  for (int pt = 0; pt < 16; ++pt) {
    {
      const int p = lane, dq = wave;
      float cp = 0.f;
#pragma unroll
      for (int i2 = 0; i2 < 8; ++i2) {
        const int d0 = dq * 16 + i2 * 2;
        const float e0 = __expf(bf2f(Qg[(size_t)d0 * 1024 + pt * 64 + p]));
        const float e1 = __expf(bf2f(Qg[(size_t)(d0 + 1) * 1024 + pt * 64 + p]));
        cp += e0 + e1;
        const unsigned int pk =
            (unsigned int)f2bf(e0) | ((unsigned int)f2bf(e1) << 16);
        *(unsigned int*)(bufA + p * 72 + d0) = pk;   // expQ^T[p][d]
      }
      Pc[dq * 64 + p] = cp;
    }
    __syncthreads();
    if (t < 64) csS[t] = 0.125f / (Pc[t] + Pc[64 + t] + Pc[128 + t] + Pc[192 + t]);
    __syncthreads();
#pragma unroll
    for (int ps = 0; ps < 4; ++ps) {
      f32x4 oc = {};
      short8 b0 = *(const short8*)(bufA + (ps * 16 + (lane & 15)) * 72 + (lane >> 4) * 8);
      short8 b1 = *(const short8*)(bufA + (ps * 16 + (lane & 15)) * 72 + 32 + (lane >> 4) * 8);
      oc = __builtin_amdgcn_mfma_f32_16x16x32_bf16(a0, b0, oc, 0, 0, 0);
      oc = __builtin_amdgcn_mfma_f32_16x16x32_bf16(a1, b1, oc, 0, 0, 0);
      const float cs = csS[ps * 16 + (lane & 15)];
      const unsigned long long pk =
          (unsigned long long)f2bf(oc[0] * cs) |
          ((unsigned long long)f2bf(oc[1] * cs) << 16) |
          ((unsigned long long)f2bf(oc[2] * cs) << 32) |
          ((unsigned long long)f2bf(oc[3] * cs) << 48);
      const int p = pt * 64 + ps * 16 + (lane & 15);
      *(unsigned long long*)(oBase + (size_t)p * 512 + wave * 16 + (lane >> 4) * 4) = pk;
    }
    __syncthreads();
  }
}

// ---------------------------------------------------------------------------
extern "C" void kernel_launch(void* const* d_in, const int* in_sizes, int n_in,
                              void* d_out, int out_size, void* d_ws, size_t ws_size,
                              hipStream_t stream) {
  (void)in_sizes; (void)n_in; (void)out_size; (void)ws_size;
  const float* x     = (const float*)d_in[0];
  const float* g_in  = (const float*)d_in[1];
  const float* w_qkv = (const float*)d_in[2];
  const float* memkv = (const float*)d_in[3];
  const float* w_out = (const float*)d_in[4];
  const float* b_out = (const float*)d_in[5];
  const float* g_out = (const float*)d_in[6];
  float* out = (float*)d_out;

  // d_ws layout — peak 69,468,160 B (66.3 MiB)
  char* ws = (char*)d_ws;
  unsigned short* wqb = (unsigned short*)(ws + 262144);    // 1.5 MiB
  unsigned short* wob = (unsigned short*)(ws + 1835008);   // 0.5 MiB
  unsigned short* xnT = (unsigned short*)(ws + 2359296);   // 32 MiB (→ outT)
  unsigned short* Qp  = (unsigned short*)(ws + 35913728);  // 32 MiB (→ pre)
  unsigned short* outT = xnT;
  unsigned short* pre  = Qp;
  // K/V live in d_out (exactly 64 MiB); d_out fully rewritten by norm_scale.
  unsigned short* Kp  = (unsigned short*)d_out;
  unsigned short* Vp  = (unsigned short*)d_out + 16777216;

  xnorm_t<<<1024, 256, 0, stream>>>(x, xnT);
  cast_wqkv<<<3072, 256, 0, stream>>>(w_qkv, g_in, wqb);
  cast_w<<<1024, 256, 0, stream>>>(w_out, wob, 262144);
  gemm_bt<1536, true, false><<<dim3(96, 32), 256, 0, stream>>>(
      wqb, xnT, Qp, Kp, Vp, nullptr);
  attn_kernel<<<256, 256, 0, stream>>>(Qp, Kp, Vp, memkv, outT);
  gemm_bt<512, false, true><<<dim3(32, 32), 256, 0, stream>>>(
      wob, outT, pre, nullptr, nullptr, b_out);
  norm_scale<<<512, 256, 0, stream>>>(pre, g_out, out);
}